// Round 11
// baseline (161.321 us; speedup 1.0000x reference)
//
#include <hip/hip_runtime.h>
#include <hip/hip_bf16.h>
#include <stdint.h>

#define Bsz 4096
#define Csz 1024

typedef __attribute__((ext_vector_type(8))) short short8;
typedef __attribute__((ext_vector_type(4))) float f32x4;

// order-preserving f32 -> u32 encoding (monotone for all non-NaN)
__device__ __forceinline__ unsigned fenc(float v) {
  unsigned u = __float_as_uint(v);
  return (u & 0x80000000u) ? ~u : (u | 0x80000000u);
}

__device__ __forceinline__ void load_lds16(const void* g, void* l) {
  __builtin_amdgcn_global_load_lds(
      (const __attribute__((address_space(1))) void*)g,
      (__attribute__((address_space(3))) void*)l, 16, 0, 0);
}

__device__ __forceinline__ uint32_t rotl32(uint32_t x, int r) {
  return (x << r) | (x >> (32 - r));
}

// ---------------- K1: row stats + bf16 cast + fused threefry rand_idx -------
__global__ __launch_bounds__(256) void k_rowstats(
    const float* __restrict__ outs, const int* __restrict__ label,
    unsigned short* __restrict__ xb, float* __restrict__ sq,
    float* __restrict__ ce, unsigned long long* __restrict__ hard,
    int* __restrict__ ridx) {
  const int row = blockIdx.x;
  const int tid = threadIdx.x;
  const int lane = tid & 63, wid = tid >> 6;
  const float4 v = reinterpret_cast<const float4*>(outs + (size_t)row * Csz)[tid];

  ushort4 u4;
  {
    __hip_bfloat16 h;
    h = __float2bfloat16(v.x); u4.x = *reinterpret_cast<const unsigned short*>(&h);
    h = __float2bfloat16(v.y); u4.y = *reinterpret_cast<const unsigned short*>(&h);
    h = __float2bfloat16(v.z); u4.z = *reinterpret_cast<const unsigned short*>(&h);
    h = __float2bfloat16(v.w); u4.w = *reinterpret_cast<const unsigned short*>(&h);
  }
  reinterpret_cast<ushort4*>(xb + (size_t)row * Csz)[tid] = u4;

  __shared__ float wred[3][4];
  float mx = fmaxf(fmaxf(v.x, v.y), fmaxf(v.z, v.w));
#pragma unroll
  for (int off = 32; off; off >>= 1) mx = fmaxf(mx, __shfl_xor(mx, off, 64));
  if (lane == 0) wred[0][wid] = mx;
  __syncthreads();
  mx = fmaxf(fmaxf(wred[0][0], wred[0][1]), fmaxf(wred[0][2], wred[0][3]));

  float se = expf(v.x - mx) + expf(v.y - mx) + expf(v.z - mx) + expf(v.w - mx);
  float s2 = v.x * v.x + v.y * v.y + v.z * v.z + v.w * v.w;
#pragma unroll
  for (int off = 32; off; off >>= 1) {
    se += __shfl_xor(se, off, 64);
    s2 += __shfl_xor(s2, off, 64);
  }
  if (lane == 0) { wred[1][wid] = se; wred[2][wid] = s2; }
  __syncthreads();
  if (tid == 0) {
    const float set = wred[1][0] + wred[1][1] + wred[1][2] + wred[1][3];
    const float sqt = wred[2][0] + wred[2][1] + wred[2][2] + wred[2][3];
    sq[row] = sqt;
    ce[row] = -(outs[(size_t)row * Csz + label[row]] - mx - logf(set));
    hard[row] = 0ull;  // fused memset
  }

  if (row >= 2048) return;

  // ---- fused rand_idx: rows row and row+2048 ----
  const int i = row;
  const int li0 = label[i], li1 = label[i + 2048];
  const uint32_t k1c = 42u, k2c = 0x1BD11BDAu ^ 42u;
  unsigned long long b0 = 0ull, b1 = 0ull;
  for (int j = tid; j < Bsz; j += 256) {
    uint32_t x0 = (uint32_t)(i * Bsz + j);
    uint32_t x1 = x0 + 8388608u;
    x1 += k1c;
#define RND(rt) { x0 += x1; x1 = rotl32(x1, rt); x1 ^= x0; }
    RND(13) RND(15) RND(26) RND(6)
    x0 += k1c; x1 += k2c + 1u;
    RND(17) RND(29) RND(16) RND(24)
    x0 += k2c; x1 += 2u;
    RND(13) RND(15) RND(26) RND(6)
    x1 += k1c + 3u;
    RND(17) RND(29) RND(16) RND(24)
    x0 += k1c; x1 += k2c + 4u;
    RND(13) RND(15) RND(26) RND(6)
    x0 += k2c; x1 += 5u;
#undef RND
    const int lj = label[j];
    if (lj != li0) {
      unsigned long long p = (((unsigned long long)(x0 >> 9)) << 32) | (uint32_t)(~j);
      if (p > b0) b0 = p;
    }
    if (lj != li1) {
      unsigned long long p = (((unsigned long long)(x1 >> 9)) << 32) | (uint32_t)(~j);
      if (p > b1) b1 = p;
    }
  }
#pragma unroll
  for (int off = 32; off; off >>= 1) {
    unsigned long long o0 = __shfl_xor(b0, off, 64); if (o0 > b0) b0 = o0;
    unsigned long long o1 = __shfl_xor(b1, off, 64); if (o1 > b1) b1 = o1;
  }
  __shared__ unsigned long long r0[4], r1[4];
  if (lane == 0) { r0[wid] = b0; r1[wid] = b1; }
  __syncthreads();
  if (tid == 0) {
#pragma unroll
    for (int w = 1; w < 4; ++w) {
      if (r0[w] > b0) b0 = r0[w];
      if (r1[w] > b1) b1 = r1[w];
    }
    ridx[i] = (int)(~(uint32_t)b0);
    ridx[i + 2048] = (int)(~(uint32_t)b1);
  }
}

// ---------------- K2: bf16 MFMA X·X^T, TRIANGULAR 128x128, dual argmax ------
// 528 blocks (tri over 32x32 tile grid, 528 = 8*66 -> bijective XCD swizzle),
// 4 waves 2x2, per-wave 64x64 = 4x4 frags of 16x16. BK=64, 16 K-tiles,
// 64KB LDS double-buffer -> 2 blocks/CU co-resident (TLP across blocks).
// r7-proven counted-vmcnt skeleton: stage 2 tiles ahead, vmcnt(8) at tile
// boundary (tile t+1's 8 insts outstanding; never 0 mid-loop), lgkmcnt(0)
// +sched_barrier+barrier WAR fence before re-staging. r3-proven swizzle:
// stored chunk-slot s of row r holds logical chunk s^(r&7), via pre-swizzled
// global source (gload_lds dest linear, rule #21); read slot (q^(fr&7)).
// Dual epilogue (r3-proven): row-side argmax + transposed col-side argmax.
__global__ __launch_bounds__(256, 2) void k_hard(
    const unsigned short* __restrict__ xb, const float* __restrict__ sq,
    const int* __restrict__ label, unsigned long long* __restrict__ hard) {
  __shared__ unsigned short As[2][128 * 64];
  __shared__ unsigned short Bs[2][128 * 64];

  const int bid = (int)blockIdx.x;
  const int swz = (bid & 7) * 66 + (bid >> 3);  // XCD swizzle (528 = 8*66)
  // triangular decode: swz -> (bi, bj), bi <= bj, 32x32 tile grid
  int rem = swz, bi = 0;
  while (rem >= 32 - bi) { rem -= 32 - bi; ++bi; }
  const int bj = bi + rem;

  const int tid = (int)threadIdx.x;
  const int wid = tid >> 6, lane = tid & 63;
  const int wr = wid >> 1, wc = wid & 1;
  const int fr = lane & 15;   // fragment row/col index
  const int fq = lane >> 4;   // k-quad index
  const int sx = fr & 7;      // read-side swizzle xor (== row&7 of lane's rows)

  f32x4 acc[4][4];
#pragma unroll
  for (int m = 0; m < 4; ++m)
#pragma unroll
    for (int n = 0; n < 4; ++n) acc[m][n] = (f32x4){0.f, 0.f, 0.f, 0.f};

  const unsigned short* Ag = xb + (size_t)(bi * 128) * Csz;
  const unsigned short* Bg = xb + (size_t)(bj * 128) * Csz;
  const int lrow = lane >> 3;                 // row within 8-row staging inst
  const int lch = ((lane & 7) ^ lrow) * 8;    // pre-swizzled source chunk

  auto STAGE = [&](int buf, int kt) {         // 8 insts/wave
#pragma unroll
    for (int c = 0; c < 4; ++c) {
      const int r = wid * 32 + c * 8;
      load_lds16(Ag + (size_t)(r + lrow) * Csz + kt + lch, &As[buf][r * 64]);
      load_lds16(Bg + (size_t)(r + lrow) * Csz + kt + lch, &Bs[buf][r * 64]);
    }
  };
  auto COMPUTE = [&](int buf) {
#pragma unroll
    for (int ks = 0; ks < 2; ++ks) {
      const int choff = ((ks * 4 + fq) ^ sx) * 8;  // swizzled chunk slot
      short8 a[4], b[4];
#pragma unroll
      for (int m = 0; m < 4; ++m)
        a[m] = *reinterpret_cast<const short8*>(
            &As[buf][(wr * 64 + m * 16 + fr) * 64 + choff]);
#pragma unroll
      for (int n = 0; n < 4; ++n)
        b[n] = *reinterpret_cast<const short8*>(
            &Bs[buf][(wc * 64 + n * 16 + fr) * 64 + choff]);
      __builtin_amdgcn_s_setprio(1);
#pragma unroll
      for (int m = 0; m < 4; ++m)
#pragma unroll
        for (int n = 0; n < 4; ++n)
          acc[m][n] = __builtin_amdgcn_mfma_f32_16x16x32_bf16(a[m], b[n], acc[m][n], 0, 0, 0);
      __builtin_amdgcn_s_setprio(0);
    }
  };

  STAGE(0, 0);
  STAGE(1, 64);
#pragma unroll 1
  for (int t = 0; t < 14; ++t) {
    asm volatile("s_waitcnt vmcnt(8)" ::: "memory");  // tile t landed (t+1 in flight)
    __builtin_amdgcn_sched_barrier(0);
    __builtin_amdgcn_s_barrier();
    COMPUTE(t & 1);
    asm volatile("s_waitcnt lgkmcnt(0)" ::: "memory");  // this wave's LDS reads done
    __builtin_amdgcn_sched_barrier(0);
    __builtin_amdgcn_s_barrier();                       // all waves done -> WAR safe
    STAGE(t & 1, (t + 2) * 64);                         // restage consumed buffer
  }
  asm volatile("s_waitcnt vmcnt(8)" ::: "memory");  // tile 14 landed
  __builtin_amdgcn_sched_barrier(0);
  __builtin_amdgcn_s_barrier();
  COMPUTE(0);
  asm volatile("s_waitcnt vmcnt(0)" ::: "memory");  // tile 15 landed
  __builtin_amdgcn_sched_barrier(0);
  __builtin_amdgcn_s_barrier();
  COMPUTE(1);

  const float cst = -2.0f * 1024.0f * 3.1622776601683794e-8f;  // -2*c*sqrt(1e-15)

  // row-side epilogue: C/D layout col=lane&15, row=fq*4+r
#pragma unroll
  for (int m = 0; m < 4; ++m) {
#pragma unroll
    for (int r = 0; r < 4; ++r) {
      const int i = bi * 128 + wr * 64 + m * 16 + fq * 4 + r;
      const int li = label[i];
      const float sqi = sq[i];
      float bestv = -3.0e38f;
      int bestj = 0x7FFFFFFF;
#pragma unroll
      for (int n = 0; n < 4; ++n) {
        const int j = bj * 128 + wc * 64 + n * 16 + fr;
        const float val = sqi + sq[j] - 2.0f * acc[m][n][r] + cst;
        if (label[j] != li && val > bestv) { bestv = val; bestj = j; }
      }
      unsigned long long pack =
          (bestj == 0x7FFFFFFF)
              ? 0ull
              : (((unsigned long long)fenc(bestv)) << 32) | (unsigned)(~bestj);
#pragma unroll
      for (int off = 1; off < 16; off <<= 1) {
        unsigned long long o = __shfl_xor(pack, off, 64);
        if (o > pack) pack = o;
      }
      if (fr == 0 && pack) atomicMax(&hard[i], pack);
    }
  }

  // column-side epilogue (transpose) for off-diagonal tiles
  if (bi != bj) {
#pragma unroll
    for (int n = 0; n < 4; ++n) {
      const int j = bj * 128 + wc * 64 + n * 16 + fr;
      const int lj = label[j];
      const float sqj = sq[j];
      unsigned long long pack = 0ull;
#pragma unroll
      for (int m = 0; m < 4; ++m) {
#pragma unroll
        for (int r = 0; r < 4; ++r) {
          const int i = bi * 128 + wr * 64 + m * 16 + fq * 4 + r;
          if (label[i] != lj) {
            const float val = sq[i] + sqj - 2.0f * acc[m][n][r] + cst;
            const unsigned long long p =
                (((unsigned long long)fenc(val)) << 32) | (unsigned)(~i);
            if (p > pack) pack = p;
          }
        }
      }
      unsigned long long o;
      o = __shfl_xor(pack, 16, 64); if (o > pack) pack = o;
      o = __shfl_xor(pack, 32, 64); if (o > pack) pack = o;
      if (fq == 0 && pack) atomicMax(&hard[j], pack);
    }
  }
}

// ---------------- K4: InfoNCE per-row term (3 f32 dots + log_softmax) --------
__global__ __launch_bounds__(256) void k_nce(
    const float* __restrict__ outs, const float* __restrict__ centers,
    const int* __restrict__ label, const unsigned long long* __restrict__ hard,
    const int* __restrict__ ridx, float* __restrict__ nce) {
  const int i = blockIdx.x;
  const int tid = threadIdx.x;
  const int lane = tid & 63, wid = tid >> 6;
  const int li = label[i];
  const int jh = (int)(~(uint32_t)hard[i]);
  const int jr = ridx[i];
  const float4 a  = reinterpret_cast<const float4*>(outs + (size_t)i * Csz)[tid];
  const float4 c  = reinterpret_cast<const float4*>(centers + (size_t)li * Csz)[tid];
  const float4 rr = reinterpret_cast<const float4*>(outs + (size_t)jr * Csz)[tid];
  const float4 hh = reinterpret_cast<const float4*>(outs + (size_t)jh * Csz)[tid];
  float dp = a.x * c.x + a.y * c.y + a.z * c.z + a.w * c.w;
  float dr = a.x * rr.x + a.y * rr.y + a.z * rr.z + a.w * rr.w;
  float dh = a.x * hh.x + a.y * hh.y + a.z * hh.z + a.w * hh.w;
#pragma unroll
  for (int off = 32; off; off >>= 1) {
    dp += __shfl_xor(dp, off, 64);
    dr += __shfl_xor(dr, off, 64);
    dh += __shfl_xor(dh, off, 64);
  }
  __shared__ float w0[4], w1[4], w2[4];
  if (lane == 0) { w0[wid] = dp; w1[wid] = dr; w2[wid] = dh; }
  __syncthreads();
  if (tid == 0) {
    const float l0 = w0[0] + w0[1] + w0[2] + w0[3];
    const float l1 = w1[0] + w1[1] + w1[2] + w1[3];
    const float l2 = w2[0] + w2[1] + w2[2] + w2[3];
    const float m = fmaxf(l0, fmaxf(l1, l2));
    const float lse = logf(expf(l0 - m) + expf(l1 - m) + expf(l2 - m));
    nce[i] = -(l0 - m - lse);
  }
}

// ---------------- K5: deterministic final reduction --------------------------
__global__ __launch_bounds__(1024) void k_final(
    const float* __restrict__ ce, const float* __restrict__ nce,
    float* __restrict__ out) {
  __shared__ double s[1024];
  const int tid = threadIdx.x;
  double v = 0.0;
#pragma unroll
  for (int q = 0; q < 4; ++q) {
    v += (double)ce[tid + q * 1024];
    v += 0.1 * (double)nce[tid + q * 1024];
  }
  s[tid] = v;
  __syncthreads();
  for (int off = 512; off; off >>= 1) {
    if (tid < off) s[tid] += s[tid + off];
    __syncthreads();
  }
  if (tid == 0) out[0] = (float)(s[0] / 4096.0);
}

extern "C" void kernel_launch(void* const* d_in, const int* in_sizes, int n_in,
                              void* d_out, int out_size, void* d_ws, size_t ws_size,
                              hipStream_t stream) {
  const float* outs = (const float*)d_in[0];
  const float* centers = (const float*)d_in[1];
  const int* label = (const int*)d_in[2];
  float* out = (float*)d_out;

  char* ws = (char*)d_ws;
  unsigned short* xb = (unsigned short*)ws;                            // 8 MB bf16 X
  unsigned long long* hard = (unsigned long long*)(ws + (8u << 20));   // 32 KB
  float* sq = (float*)(ws + (8u << 20) + 32768);                       // 16 KB
  float* ce = sq + Bsz;                                                // 16 KB
  float* nce = ce + Bsz;                                               // 16 KB
  int* ridx = (int*)(nce + Bsz);                                       // 16 KB

  k_rowstats<<<Bsz, 256, 0, stream>>>(outs, label, xb, sq, ce, hard, ridx);
  k_hard<<<528, 256, 0, stream>>>(xb, sq, label, hard);
  k_nce<<<Bsz, 256, 0, stream>>>(outs, centers, label, hard, ridx, nce);
  k_final<<<1, 1024, 0, stream>>>(ce, nce, out);
}

// Round 12
// 157.682 us; speedup vs baseline: 1.0231x; 1.0231x over previous
//
#include <hip/hip_runtime.h>
#include <hip/hip_bf16.h>
#include <stdint.h>

#define Bsz 4096
#define Csz 1024

typedef __attribute__((ext_vector_type(8))) short short8;
typedef __attribute__((ext_vector_type(4))) float f32x4;

// order-preserving f32 -> u32 encoding (monotone for all non-NaN)
__device__ __forceinline__ unsigned fenc(float v) {
  unsigned u = __float_as_uint(v);
  return (u & 0x80000000u) ? ~u : (u | 0x80000000u);
}

__device__ __forceinline__ float b2f(unsigned short u) {
  return __uint_as_float(((unsigned)u) << 16);
}

__device__ __forceinline__ void load_lds16(const void* g, void* l) {
  __builtin_amdgcn_global_load_lds(
      (const __attribute__((address_space(1))) void*)g,
      (__attribute__((address_space(3))) void*)l, 16, 0, 0);
}

__device__ __forceinline__ uint32_t rotl32(uint32_t x, int r) {
  return (x << r) | (x >> (32 - r));
}

// ---------------- K1: row stats + bf16 cast + fused threefry rand_idx -------
__global__ __launch_bounds__(256) void k_rowstats(
    const float* __restrict__ outs, const int* __restrict__ label,
    unsigned short* __restrict__ xb, float* __restrict__ sq,
    float* __restrict__ ce, unsigned long long* __restrict__ hard,
    int* __restrict__ ridx) {
  const int row = blockIdx.x;
  const int tid = threadIdx.x;
  const int lane = tid & 63, wid = tid >> 6;
  const float4 v = reinterpret_cast<const float4*>(outs + (size_t)row * Csz)[tid];

  ushort4 u4;
  {
    __hip_bfloat16 h;
    h = __float2bfloat16(v.x); u4.x = *reinterpret_cast<const unsigned short*>(&h);
    h = __float2bfloat16(v.y); u4.y = *reinterpret_cast<const unsigned short*>(&h);
    h = __float2bfloat16(v.z); u4.z = *reinterpret_cast<const unsigned short*>(&h);
    h = __float2bfloat16(v.w); u4.w = *reinterpret_cast<const unsigned short*>(&h);
  }
  reinterpret_cast<ushort4*>(xb + (size_t)row * Csz)[tid] = u4;

  __shared__ float wred[3][4];
  float mx = fmaxf(fmaxf(v.x, v.y), fmaxf(v.z, v.w));
#pragma unroll
  for (int off = 32; off; off >>= 1) mx = fmaxf(mx, __shfl_xor(mx, off, 64));
  if (lane == 0) wred[0][wid] = mx;
  __syncthreads();
  mx = fmaxf(fmaxf(wred[0][0], wred[0][1]), fmaxf(wred[0][2], wred[0][3]));

  float se = expf(v.x - mx) + expf(v.y - mx) + expf(v.z - mx) + expf(v.w - mx);
  float s2 = v.x * v.x + v.y * v.y + v.z * v.z + v.w * v.w;
#pragma unroll
  for (int off = 32; off; off >>= 1) {
    se += __shfl_xor(se, off, 64);
    s2 += __shfl_xor(s2, off, 64);
  }
  if (lane == 0) { wred[1][wid] = se; wred[2][wid] = s2; }
  __syncthreads();
  if (tid == 0) {
    const float set = wred[1][0] + wred[1][1] + wred[1][2] + wred[1][3];
    const float sqt = wred[2][0] + wred[2][1] + wred[2][2] + wred[2][3];
    sq[row] = sqt;
    ce[row] = -(outs[(size_t)row * Csz + label[row]] - mx - logf(set));
    hard[row] = 0ull;  // fused memset
  }

  if (row >= 2048) return;

  // ---- fused rand_idx: rows row and row+2048 ----
  const int i = row;
  const int li0 = label[i], li1 = label[i + 2048];
  const uint32_t k1c = 42u, k2c = 0x1BD11BDAu ^ 42u;
  unsigned long long b0 = 0ull, b1 = 0ull;
  for (int j = tid; j < Bsz; j += 256) {
    uint32_t x0 = (uint32_t)(i * Bsz + j);
    uint32_t x1 = x0 + 8388608u;
    x1 += k1c;
#define RND(rt) { x0 += x1; x1 = rotl32(x1, rt); x1 ^= x0; }
    RND(13) RND(15) RND(26) RND(6)
    x0 += k1c; x1 += k2c + 1u;
    RND(17) RND(29) RND(16) RND(24)
    x0 += k2c; x1 += 2u;
    RND(13) RND(15) RND(26) RND(6)
    x1 += k1c + 3u;
    RND(17) RND(29) RND(16) RND(24)
    x0 += k1c; x1 += k2c + 4u;
    RND(13) RND(15) RND(26) RND(6)
    x0 += k2c; x1 += 5u;
#undef RND
    const int lj = label[j];
    if (lj != li0) {
      unsigned long long p = (((unsigned long long)(x0 >> 9)) << 32) | (uint32_t)(~j);
      if (p > b0) b0 = p;
    }
    if (lj != li1) {
      unsigned long long p = (((unsigned long long)(x1 >> 9)) << 32) | (uint32_t)(~j);
      if (p > b1) b1 = p;
    }
  }
#pragma unroll
  for (int off = 32; off; off >>= 1) {
    unsigned long long o0 = __shfl_xor(b0, off, 64); if (o0 > b0) b0 = o0;
    unsigned long long o1 = __shfl_xor(b1, off, 64); if (o1 > b1) b1 = o1;
  }
  __shared__ unsigned long long r0[4], r1[4];
  if (lane == 0) { r0[wid] = b0; r1[wid] = b1; }
  __syncthreads();
  if (tid == 0) {
#pragma unroll
    for (int w = 1; w < 4; ++w) {
      if (r0[w] > b0) b0 = r0[w];
      if (r1[w] > b1) b1 = r1[w];
    }
    ridx[i] = (int)(~(uint32_t)b0);
    ridx[i + 2048] = (int)(~(uint32_t)b1);
  }
}

// ---------------- K2: bf16 MFMA X·X^T, TRIANGULAR 128x128, dual argmax ------
// (byte-identical to r11: 528 tri blocks, 4 waves 2x2, BK=64, 2 blocks/CU,
// counted vmcnt(8), lgkmcnt(0)+sched_barrier WAR fence, 8-slot swizzle,
// dual row/col argmax epilogue. 0 bank conflicts, absmax 0 proven.)
__global__ __launch_bounds__(256, 2) void k_hard(
    const unsigned short* __restrict__ xb, const float* __restrict__ sq,
    const int* __restrict__ label, unsigned long long* __restrict__ hard) {
  __shared__ unsigned short As[2][128 * 64];
  __shared__ unsigned short Bs[2][128 * 64];

  const int bid = (int)blockIdx.x;
  const int swz = (bid & 7) * 66 + (bid >> 3);  // XCD swizzle (528 = 8*66)
  int rem = swz, bi = 0;
  while (rem >= 32 - bi) { rem -= 32 - bi; ++bi; }
  const int bj = bi + rem;

  const int tid = (int)threadIdx.x;
  const int wid = tid >> 6, lane = tid & 63;
  const int wr = wid >> 1, wc = wid & 1;
  const int fr = lane & 15;
  const int fq = lane >> 4;
  const int sx = fr & 7;

  f32x4 acc[4][4];
#pragma unroll
  for (int m = 0; m < 4; ++m)
#pragma unroll
    for (int n = 0; n < 4; ++n) acc[m][n] = (f32x4){0.f, 0.f, 0.f, 0.f};

  const unsigned short* Ag = xb + (size_t)(bi * 128) * Csz;
  const unsigned short* Bg = xb + (size_t)(bj * 128) * Csz;
  const int lrow = lane >> 3;
  const int lch = ((lane & 7) ^ lrow) * 8;

  auto STAGE = [&](int buf, int kt) {
#pragma unroll
    for (int c = 0; c < 4; ++c) {
      const int r = wid * 32 + c * 8;
      load_lds16(Ag + (size_t)(r + lrow) * Csz + kt + lch, &As[buf][r * 64]);
      load_lds16(Bg + (size_t)(r + lrow) * Csz + kt + lch, &Bs[buf][r * 64]);
    }
  };
  auto COMPUTE = [&](int buf) {
#pragma unroll
    for (int ks = 0; ks < 2; ++ks) {
      const int choff = ((ks * 4 + fq) ^ sx) * 8;
      short8 a[4], b[4];
#pragma unroll
      for (int m = 0; m < 4; ++m)
        a[m] = *reinterpret_cast<const short8*>(
            &As[buf][(wr * 64 + m * 16 + fr) * 64 + choff]);
#pragma unroll
      for (int n = 0; n < 4; ++n)
        b[n] = *reinterpret_cast<const short8*>(
            &Bs[buf][(wc * 64 + n * 16 + fr) * 64 + choff]);
      __builtin_amdgcn_s_setprio(1);
#pragma unroll
      for (int m = 0; m < 4; ++m)
#pragma unroll
        for (int n = 0; n < 4; ++n)
          acc[m][n] = __builtin_amdgcn_mfma_f32_16x16x32_bf16(a[m], b[n], acc[m][n], 0, 0, 0);
      __builtin_amdgcn_s_setprio(0);
    }
  };

  STAGE(0, 0);
  STAGE(1, 64);
#pragma unroll 1
  for (int t = 0; t < 14; ++t) {
    asm volatile("s_waitcnt vmcnt(8)" ::: "memory");
    __builtin_amdgcn_sched_barrier(0);
    __builtin_amdgcn_s_barrier();
    COMPUTE(t & 1);
    asm volatile("s_waitcnt lgkmcnt(0)" ::: "memory");
    __builtin_amdgcn_sched_barrier(0);
    __builtin_amdgcn_s_barrier();
    STAGE(t & 1, (t + 2) * 64);
  }
  asm volatile("s_waitcnt vmcnt(8)" ::: "memory");
  __builtin_amdgcn_sched_barrier(0);
  __builtin_amdgcn_s_barrier();
  COMPUTE(0);
  asm volatile("s_waitcnt vmcnt(0)" ::: "memory");
  __builtin_amdgcn_sched_barrier(0);
  __builtin_amdgcn_s_barrier();
  COMPUTE(1);

  const float cst = -2.0f * 1024.0f * 3.1622776601683794e-8f;  // -2*c*sqrt(1e-15)

  // row-side epilogue: C/D layout col=lane&15, row=fq*4+r
#pragma unroll
  for (int m = 0; m < 4; ++m) {
#pragma unroll
    for (int r = 0; r < 4; ++r) {
      const int i = bi * 128 + wr * 64 + m * 16 + fq * 4 + r;
      const int li = label[i];
      const float sqi = sq[i];
      float bestv = -3.0e38f;
      int bestj = 0x7FFFFFFF;
#pragma unroll
      for (int n = 0; n < 4; ++n) {
        const int j = bj * 128 + wc * 64 + n * 16 + fr;
        const float val = sqi + sq[j] - 2.0f * acc[m][n][r] + cst;
        if (label[j] != li && val > bestv) { bestv = val; bestj = j; }
      }
      unsigned long long pack =
          (bestj == 0x7FFFFFFF)
              ? 0ull
              : (((unsigned long long)fenc(bestv)) << 32) | (unsigned)(~bestj);
#pragma unroll
      for (int off = 1; off < 16; off <<= 1) {
        unsigned long long o = __shfl_xor(pack, off, 64);
        if (o > pack) pack = o;
      }
      if (fr == 0 && pack) atomicMax(&hard[i], pack);
    }
  }

  // column-side epilogue (transpose) for off-diagonal tiles
  if (bi != bj) {
#pragma unroll
    for (int n = 0; n < 4; ++n) {
      const int j = bj * 128 + wc * 64 + n * 16 + fr;
      const int lj = label[j];
      const float sqj = sq[j];
      unsigned long long pack = 0ull;
#pragma unroll
      for (int m = 0; m < 4; ++m) {
#pragma unroll
        for (int r = 0; r < 4; ++r) {
          const int i = bi * 128 + wr * 64 + m * 16 + fq * 4 + r;
          if (label[i] != lj) {
            const float val = sq[i] + sqj - 2.0f * acc[m][n][r] + cst;
            const unsigned long long p =
                (((unsigned long long)fenc(val)) << 32) | (unsigned)(~i);
            if (p > pack) pack = p;
          }
        }
      }
      unsigned long long o;
      o = __shfl_xor(pack, 16, 64); if (o > pack) pack = o;
      o = __shfl_xor(pack, 32, 64); if (o > pack) pack = o;
      if (fq == 0 && pack) atomicMax(&hard[j], pack);
    }
  }
}

// ---------------- K4: InfoNCE per-row, bf16 gathers, fused ce ---------------
// Rows i, jr, jh read from bf16 xb (10 KB/block vs 16 KB f32); centers stays
// f32 (no bf16 copy exists). Logit error ~0.1 on sigma~32 -> loss delta
// ~5e-4 << 0.185 threshold. Writes tot[i] = ce[i] + 0.1*nce_i.
__global__ __launch_bounds__(256) void k_nce(
    const unsigned short* __restrict__ xb, const float* __restrict__ centers,
    const int* __restrict__ label, const unsigned long long* __restrict__ hard,
    const int* __restrict__ ridx, const float* __restrict__ ce,
    float* __restrict__ tot) {
  const int i = blockIdx.x;
  const int tid = threadIdx.x;
  const int lane = tid & 63, wid = tid >> 6;
  const int li = label[i];
  const int jh = (int)(~(uint32_t)hard[i]);
  const int jr = ridx[i];
  const ushort4 xi = reinterpret_cast<const ushort4*>(xb + (size_t)i * Csz)[tid];
  const float4  cc = reinterpret_cast<const float4*>(centers + (size_t)li * Csz)[tid];
  const ushort4 rr = reinterpret_cast<const ushort4*>(xb + (size_t)jr * Csz)[tid];
  const ushort4 hh = reinterpret_cast<const ushort4*>(xb + (size_t)jh * Csz)[tid];
  const float x0 = b2f(xi.x), x1 = b2f(xi.y), x2 = b2f(xi.z), x3 = b2f(xi.w);
  float dp = x0 * cc.x + x1 * cc.y + x2 * cc.z + x3 * cc.w;
  float dr = x0 * b2f(rr.x) + x1 * b2f(rr.y) + x2 * b2f(rr.z) + x3 * b2f(rr.w);
  float dh = x0 * b2f(hh.x) + x1 * b2f(hh.y) + x2 * b2f(hh.z) + x3 * b2f(hh.w);
#pragma unroll
  for (int off = 32; off; off >>= 1) {
    dp += __shfl_xor(dp, off, 64);
    dr += __shfl_xor(dr, off, 64);
    dh += __shfl_xor(dh, off, 64);
  }
  __shared__ float w0[4], w1[4], w2[4];
  if (lane == 0) { w0[wid] = dp; w1[wid] = dr; w2[wid] = dh; }
  __syncthreads();
  if (tid == 0) {
    const float l0 = w0[0] + w0[1] + w0[2] + w0[3];
    const float l1 = w1[0] + w1[1] + w1[2] + w1[3];
    const float l2 = w2[0] + w2[1] + w2[2] + w2[3];
    const float m = fmaxf(l0, fmaxf(l1, l2));
    const float lse = logf(expf(l0 - m) + expf(l1 - m) + expf(l2 - m));
    tot[i] = ce[i] + 0.1f * (-(l0 - m - lse));
  }
}

// ---------------- K5: deterministic final reduction --------------------------
__global__ __launch_bounds__(1024) void k_final(
    const float* __restrict__ tot, float* __restrict__ out) {
  __shared__ double s[1024];
  const int tid = threadIdx.x;
  double v = 0.0;
#pragma unroll
  for (int q = 0; q < 4; ++q) v += (double)tot[tid + q * 1024];
  s[tid] = v;
  __syncthreads();
  for (int off = 512; off; off >>= 1) {
    if (tid < off) s[tid] += s[tid + off];
    __syncthreads();
  }
  if (tid == 0) out[0] = (float)(s[0] / 4096.0);
}

extern "C" void kernel_launch(void* const* d_in, const int* in_sizes, int n_in,
                              void* d_out, int out_size, void* d_ws, size_t ws_size,
                              hipStream_t stream) {
  const float* outs = (const float*)d_in[0];
  const float* centers = (const float*)d_in[1];
  const int* label = (const int*)d_in[2];
  float* out = (float*)d_out;

  char* ws = (char*)d_ws;
  unsigned short* xb = (unsigned short*)ws;                            // 8 MB bf16 X
  unsigned long long* hard = (unsigned long long*)(ws + (8u << 20));   // 32 KB
  float* sq = (float*)(ws + (8u << 20) + 32768);                       // 16 KB
  float* ce = sq + Bsz;                                                // 16 KB
  float* tot = ce + Bsz;                                               // 16 KB
  int* ridx = (int*)(tot + Bsz);                                       // 16 KB

  k_rowstats<<<Bsz, 256, 0, stream>>>(outs, label, xb, sq, ce, hard, ridx);
  k_hard<<<528, 256, 0, stream>>>(xb, sq, label, hard);
  k_nce<<<Bsz, 256, 0, stream>>>(xb, centers, label, hard, ridx, ce, tot);
  k_final<<<1, 1024, 0, stream>>>(tot, out);
}